// Round 1
// baseline (246.843 us; speedup 1.0000x reference)
//
#include <hip/hip_runtime.h>
#include <hip/hip_bf16.h>
#include <math.h>

// Problem dims (fixed by reference)
#define BB 64
#define SS 200
#define TT 32
#define VV 50000
#define EE 128
#define CC 128
#define HH 100
#define G3 300           // 3*H
#define OUTD 104
#define NTREE (BB*SS)    // 12800

typedef __attribute__((ext_vector_type(4))) float f32x4;
typedef _Float16 f16x8 __attribute__((ext_vector_type(8)));

__device__ inline float fast_sigmoid(float x) {
    return __builtin_amdgcn_rcpf(1.f + __builtin_amdgcn_exp2f(-1.4426950408889634f * x));
}
__device__ inline float fast_tanh(float x) {
    return 1.f - 2.f * __builtin_amdgcn_rcpf(1.f + __builtin_amdgcn_exp2f(2.8853900817779268f * x));
}

// LDS-only barrier: waits ds-ops (lgkmcnt) but does NOT drain vmcnt, so in-flight
// global prefetch loads stay outstanding across the barrier (waited at use).
#define BAR() asm volatile("s_waitcnt lgkmcnt(0)\n\ts_barrier" ::: "memory")

// Workspace byte offsets (total 34.2 MB)
//   wl    @ 0        : 32768 B   (k1 W_lin fragment image, fp16)
//   k2b   @ 32768    : 163840 B  (k2 W_ih fragment image, fp16)
//   thi   @ 196608   : 3276800 B (tree_vec, fp16)
//   gx    @ 3473408  : 30720000 B (fp32)
//   emb16 @ 3473408  : 12800000 B -- ALIASES gx: k0 writes it, k1 reads it,
//                                   k2 overwrites gx only after k1 completes.
//   pool  @ 0        : 51200 B   -- aliases wl/k2b; k3 writes it AFTER k2 read them.

// ---------------- K0: weight-fragment images + fp16 embedding image (idempotent)
__global__ __launch_bounds__(256) void k0_prep(const float* __restrict__ w_lin,
                                               const float* __restrict__ w_ih_f,
                                               const float* __restrict__ w_ih_b,
                                               const float* __restrict__ emb,
                                               _Float16* __restrict__ wl,
                                               _Float16* __restrict__ k2b,
                                               _Float16* __restrict__ emb16) {
    const int tid  = threadIdx.x;
    const int wave = tid >> 6;
    const int lane = tid & 63;
    const int r = lane & 15;
    const int q = lane >> 4;
    if (blockIdx.x == 0) {
        // k1 image: wave w, lane(r,q), nt, kt -> W_lin[n=w*32+nt*16+r][k=kt*32+q*8 ..+8]
#pragma unroll
        for (int nt = 0; nt < 2; ++nt)
#pragma unroll
            for (int kt = 0; kt < 4; ++kt) {
                const int n = wave * 32 + nt * 16 + r;
                const float* src = w_lin + (long)n * EE + kt * 32 + q * 8;
                f16x8 f;
#pragma unroll
                for (int e = 0; e < 8; ++e) f[e] = (_Float16)src[e];
                *(f16x8*)&wl[(size_t)((((wave * 2 + nt) * 4 + kt) * 64) + lane) * 8] = f;
            }
    } else if (blockIdx.x <= 10) {
        // k2 image: nb, wave w, lane(r,q), kt -> W_ih[padded n = nb*64+w*16+r][k=kt*32+q*8]
        const int nb = blockIdx.x - 1;           // 0..9
        const int n = nb * 64 + wave * 16 + r;
        const int dir = (n >= 320) ? 1 : 0;
        const int j = n - dir * 320;
        const int jj = (j < G3) ? j : 0;         // pad rows clamped (results discarded)
        const float* w = dir ? w_ih_b : w_ih_f;
#pragma unroll
        for (int kt = 0; kt < 4; ++kt) {
            const float* src = w + (long)jj * EE + kt * 32 + q * 8;
            f16x8 f;
#pragma unroll
            for (int e = 0; e < 8; ++e) f[e] = (_Float16)src[e];
            *(f16x8*)&k2b[(size_t)((((nb * 4 + wave) * 4 + kt) * 64) + lane) * 8] = f;
        }
    } else {
        // fp16 embedding image: 50000*128 = 6,400,000 elems = 3125 blocks * 2048
        const long base = (long)(blockIdx.x - 11) * 2048 + (long)tid * 8;
        if (base < (long)VV * EE) {
            const float4* s = (const float4*)(emb + base);
            const float4 v0 = s[0], v1 = s[1];
            f16x8 f;
            f[0] = (_Float16)v0.x; f[1] = (_Float16)v0.y;
            f[2] = (_Float16)v0.z; f[3] = (_Float16)v0.w;
            f[4] = (_Float16)v1.x; f[5] = (_Float16)v1.y;
            f[6] = (_Float16)v1.z; f[7] = (_Float16)v1.w;
            *(f16x8*)&emb16[base] = f;
        }
    }
}

// ---------------- K1 (fp16 MFMA): embed-gather (fp16) -> GEMM vs W_lin^T -> bias -> tree-sum -> maxpool
#define K1_TPI 2
#define AROWS (K1_TPI*TT)        // 64
#define LDA 136                  // fp16/row: 128 + 8 pad
#define LDC 132                  // fp32/row: 128 + 4 pad

__global__ __launch_bounds__(256) void k1_mfma(const int* __restrict__ tok,
                                               const _Float16* __restrict__ emb16,
                                               const _Float16* __restrict__ wl,
                                               const float* __restrict__ b_lin,
                                               _Float16* __restrict__ thi) {
    __shared__ __align__(16) _Float16 A_sh[AROWS * LDA];   // 17408 B
    __shared__ __align__(16) float C_sh[AROWS * LDC];      // 33792 B
    __shared__ int tok_sh[AROWS];

    const int tid  = threadIdx.x;
    const int wave = tid >> 6;
    const int lane = tid & 63;
    const int r = lane & 15;
    const int q = lane >> 4;

    // ---- B fragments: 8 coalesced 16B loads from the prebuilt image (no cvt VALU)
    f16x8 bfrag[2][4];
    float bias[2];
#pragma unroll
    for (int nt = 0; nt < 2; ++nt) {
        bias[nt] = b_lin[wave * 32 + nt * 16 + r];
#pragma unroll
        for (int kt = 0; kt < 4; ++kt)
            bfrag[nt][kt] = *(const f16x8*)&wl[(size_t)((((wave * 2 + nt) * 4 + kt) * 64) + lane) * 8];
    }

    const int tree0 = blockIdx.x * K1_TPI;
    if (tid < AROWS) tok_sh[tid] = tok[tree0 * TT + tid];
    __syncthreads();

    // ---- gather fp16 embeddings -> LDS (pure 16B copies, half the global traffic)
#pragma unroll
    for (int i = 0; i < 4; ++i) {
        const int idx = tid + i * 256;       // 0..1023
        const int row = idx >> 4;            // 64 rows
        const int p   = idx & 15;            // 16 x f16x8 = 128 elems
        const f16x8 v = *(const f16x8*)&emb16[(long)tok_sh[row] * EE + p * 8];
        *(f16x8*)&A_sh[row * LDA + p * 8] = v;
    }
    __syncthreads();

    f32x4 acc[4][2];
#pragma unroll
    for (int mt = 0; mt < 4; ++mt)
#pragma unroll
        for (int nt = 0; nt < 2; ++nt) acc[mt][nt] = (f32x4)(0.f);

#pragma unroll
    for (int mt = 0; mt < 4; ++mt) {
        const int m = mt * 16 + r;
        f16x8 afrag[4];
#pragma unroll
        for (int kt = 0; kt < 4; ++kt)
            afrag[kt] = *(const f16x8*)&A_sh[m * LDA + kt * 32 + q * 8];
#pragma unroll
        for (int nt = 0; nt < 2; ++nt)
#pragma unroll
            for (int kt = 0; kt < 4; ++kt)
                acc[mt][nt] = __builtin_amdgcn_mfma_f32_16x16x32_f16(
                    afrag[kt], bfrag[nt][kt], acc[mt][nt], 0, 0, 0);
    }

#pragma unroll
    for (int mt = 0; mt < 4; ++mt)
#pragma unroll
        for (int nt = 0; nt < 2; ++nt) {
            const int col = wave * 32 + nt * 16 + r;
#pragma unroll
            for (int reg = 0; reg < 4; ++reg) {
                const int row = mt * 16 + q * 4 + reg;
                C_sh[row * LDC + col] = acc[mt][nt][reg] + bias[nt];
            }
        }
    __syncthreads();

    // ---- tree-sum + maxpool in registers (descending index = topological order)
    {
        const int t = tid >> 7;
        const int j = tid & 127;
        const float* base = &C_sh[(t * TT) * LDC + j];
        float v[TT];
#pragma unroll
        for (int n = 0; n < TT; ++n) v[n] = base[n * LDC];
        float mx = -1e30f;
#pragma unroll
        for (int n = TT - 1; n >= 1; --n) {
            mx = fmaxf(mx, v[n]);
            v[(n - 1) >> 1] += v[n];
        }
        mx = fmaxf(mx, v[0]);
        thi[(size_t)(tree0 + t) * CC + j] = (_Float16)mx;   // fp32 sums, one fp16 round
    }
}

// ---------------- K2 (fp16 MFMA): gx[dir][m=b*S+s][300] = X @ W_ih^T + b_ih
__global__ __launch_bounds__(256) void k2_mfma(const _Float16* __restrict__ thi,
                                               const _Float16* __restrict__ k2b,
                                               const float* __restrict__ b_ih_f,
                                               const float* __restrict__ b_ih_b,
                                               float* __restrict__ gx) {
    __shared__ __align__(16) _Float16 Ah[32 * LDA];   // 8704 B

    const int tid  = threadIdx.x;
    const int wave = tid >> 6;
    const int lane = tid & 63;
    const int r = lane & 15;
    const int q = lane >> 4;

    const int nb = blockIdx.x % 10;
    const int mb = blockIdx.x / 10;
    const int m0 = mb * 32;
    const int n0 = nb * 64;

    // stage A: 32 rows x 128 fp16 = 512 f16x8; 2 per thread (copy, no conversion)
#pragma unroll
    for (int i = 0; i < 2; ++i) {
        const int idx = tid + i * 256;
        const int row = idx >> 4;
        const int p   = idx & 15;
        f16x8 v = *(const f16x8*)&thi[(size_t)(m0 + row) * CC + p * 8];
        *(f16x8*)&Ah[row * LDA + p * 8] = v;
    }
    // B fragments: 4 coalesced 16B loads
    f16x8 bh[4];
#pragma unroll
    for (int kt = 0; kt < 4; ++kt)
        bh[kt] = *(const f16x8*)&k2b[(size_t)((((nb * 4 + wave) * 4 + kt) * 64) + lane) * 8];
    __syncthreads();

    f32x4 acc[2];
    acc[0] = (f32x4)(0.f); acc[1] = (f32x4)(0.f);
#pragma unroll
    for (int mt = 0; mt < 2; ++mt) {
        const int m = mt * 16 + r;
#pragma unroll
        for (int kt = 0; kt < 4; ++kt) {
            f16x8 a = *(const f16x8*)&Ah[m * LDA + kt * 32 + q * 8];
            acc[mt] = __builtin_amdgcn_mfma_f32_16x16x32_f16(a, bh[kt], acc[mt], 0, 0, 0);
        }
    }

    const int ng  = n0 + wave * 16 + r;
    const int dir = (ng >= 320) ? 1 : 0;
    const int j   = ng - dir * 320;
    const bool valid = (j < G3);
    const float bias = valid ? (dir ? b_ih_b[j] : b_ih_f[j]) : 0.f;
    float* gxd = gx + (long)dir * NTREE * G3;
    if (valid) {
#pragma unroll
        for (int mt = 0; mt < 2; ++mt)
#pragma unroll
            for (int reg = 0; reg < 4; ++reg) {
                const int m = m0 + mt * 16 + q * 4 + reg;
                gxd[(long)m * G3 + j] = acc[mt][reg] + bias;
            }
    }
}

// ---------------- K3 v6: 1 chain/block, fp16 MFMA matvec, row-permuted W_hh.
// Changes vs v5 (measured 100 us):
//  - g_sh LDS round-trip REMOVED. A-rows are replicated (same h for all 16 r-lanes),
//    so D rows are identical => acc[i][reg] identical across q and reg. A 3-cndmask
//    q-select puts gh[row lane] into V1 at every lane; the 3 gate values per channel
//    then come from the lane's own V1 plus 3 ds_bpermute (__shfl) pulls.
//  - MFMA dependency depth 4 -> 2 (split-K accumulator pair, one scalar add).
//  - gx prefetch depth 1 -> 2 steps (L3 cross-XCD latency ~600cy fully hidden).
__global__ __launch_bounds__(256, 1) void k3_gru(const float* __restrict__ gx,
                                                 const float* __restrict__ w_hh_f,
                                                 const float* __restrict__ b_hh_f,
                                                 const float* __restrict__ w_hh_b,
                                                 const float* __restrict__ b_hh_b,
                                                 float* __restrict__ pool) {
    const int bid = blockIdx.x;   // 0..127
    const int dir = bid & 1;
    const int b = bid >> 1;
    const float* w_hh = dir ? w_hh_b : w_hh_f;
    const float* b_hh = dir ? b_hh_b : b_hh_f;

    __shared__ __align__(16) _Float16 h_sh[2][128];

    const int tid  = threadIdx.x;
    const int wave = tid >> 6;
    const int lane = tid & 63;
    const int r = lane & 15;
    const int q = lane >> 4;

    // W_hh fragments, row-permuted: tile i, lane r -> l=i*16+r; gate=l/25, ch=l-25*gate;
    // actual row = gate*H + wave*25 + ch  (rows l>=75 zero-padded)
    f16x8 bf[5][4];
#pragma unroll
    for (int i = 0; i < 5; ++i) {
        const int l = i * 16 + r;
        const int gate = l / 25;
        const int ch   = l - gate * 25;
        const bool nv  = (l < 75);
        const int row  = gate * HH + wave * 25 + ch;
#pragma unroll
        for (int kt = 0; kt < 4; ++kt) {
            f16x8 f;
#pragma unroll
            for (int e = 0; e < 8; ++e) {
                const int k = kt * 32 + q * 8 + e;
                f[e] = (_Float16)((nv && k < HH) ? w_hh[row * HH + k] : 0.f);
            }
            bf[i][kt] = f;
        }
    }

    const int m = lane;
    const int c = wave * 25 + m;
    const bool act = (m < 25);
    float br = 0.f, bz = 0.f, bn = 0.f;
    if (act) { br = b_hh[c]; bz = b_hh[HH + c]; bn = b_hh[2 * HH + c]; }

    // bpermute source lanes: V1 at lane l holds gh[l] (l<64); g4 at lane r holds gh[64+r]
    const int a_z  = (25 + m) & 63;          // row 25+m
    const int a_n1 = (50 + m) & 63;          // row 50+m if < 64
    const int a_n2 = (50 + m - 64) & 63;     // row 50+m if >= 64 (from g4)
    const bool nV1 = (50 + m) < 64;

    if (tid < 128) { h_sh[0][tid] = (_Float16)0.f; h_sh[1][tid] = (_Float16)0.f; }

    const float* gxd = gx + (long)dir * NTREE * G3;
    const int sstep = dir ? -1 : 1;
    int s = dir ? (SS - 1) : 0;
    float xr = 0.f, xz = 0.f, xn = 0.f;      // current step
    float xr1 = 0.f, xz1 = 0.f, xn1 = 0.f;   // +1 step
    if (act) {
        const float* r0 = gxd + ((long)b * SS + s) * G3;
        xr = r0[c]; xz = r0[HH + c]; xn = r0[2 * HH + c];
        const float* r1 = gxd + ((long)b * SS + s + sstep) * G3;
        xr1 = r1[c]; xz1 = r1[HH + c]; xn1 = r1[2 * HH + c];
    }
    float hj = 0.f, hmax = -1e30f;
    __syncthreads();

    for (int t = 0; t < SS; ++t) {
        const int p = t & 1;
        float xr2 = 0.f, xz2 = 0.f, xn2 = 0.f;   // +2 step prefetch
        if (act && t < SS - 2) {
            const float* r2 = gxd + ((long)b * SS + (s + 2 * sstep)) * G3;
            xr2 = r2[c]; xz2 = r2[HH + c]; xn2 = r2[2 * HH + c];
        }

        f16x8 a[4];
#pragma unroll
        for (int kt = 0; kt < 4; ++kt)
            a[kt] = *(const f16x8*)&h_sh[p][kt * 32 + q * 8];

        // split-K: two parallel depth-2 chains per tile
        f32x4 accA[5], accB[5];
#pragma unroll
        for (int i = 0; i < 5; ++i) {
            accA[i] = (f32x4)(0.f);
            accB[i] = (f32x4)(0.f);
            accA[i] = __builtin_amdgcn_mfma_f32_16x16x32_f16(a[0], bf[i][0], accA[i], 0, 0, 0);
            accB[i] = __builtin_amdgcn_mfma_f32_16x16x32_f16(a[2], bf[i][2], accB[i], 0, 0, 0);
            accA[i] = __builtin_amdgcn_mfma_f32_16x16x32_f16(a[1], bf[i][1], accA[i], 0, 0, 0);
            accB[i] = __builtin_amdgcn_mfma_f32_16x16x32_f16(a[3], bf[i][3], accB[i], 0, 0, 0);
        }
        const float g0 = accA[0][0] + accB[0][0];
        const float g1 = accA[1][0] + accB[1][0];
        const float g2 = accA[2][0] + accB[2][0];
        const float g3 = accA[3][0] + accB[3][0];
        const float g4 = accA[4][0] + accB[4][0];
        // V1 at lane l = gh[row l]  (rows 0..63); g4 at lane r = gh[64+r] (rows 64..74)
        float V1 = g0;
        V1 = (q == 1) ? g1 : V1;
        V1 = (q == 2) ? g2 : V1;
        V1 = (q == 3) ? g3 : V1;
        const float ghr = V1;                    // row m == own lane
        const float ghz = __shfl(V1, a_z);       // row 25+m
        const float vnA = __shfl(V1, a_n1);
        const float vnB = __shfl(g4, a_n2);
        const float ghn = nV1 ? vnA : vnB;       // row 50+m

        if (act) {
            const float rg = fast_sigmoid(xr + ghr + br);
            const float zg = fast_sigmoid(xz + ghz + bz);
            const float ng = fast_tanh(xn + rg * (ghn + bn));
            hj = (1.f - zg) * ng + zg * hj;
            h_sh[1 - p][c] = (_Float16)hj;
            hmax = fmaxf(hmax, hj);
            xr = xr1; xz = xz1; xn = xn1;
            xr1 = xr2; xz1 = xz2; xn1 = xn2;
        }
        BAR();
        s += sstep;
    }
    if (act) pool[(long)b * (2 * HH) + dir * HH + c] = hmax;
}

// ---------------- K4: out[b][o] = fc_b[o] + pool[b,:] . fc_w[o,:]
__global__ __launch_bounds__(256) void k4_fc(const float* __restrict__ pool,
                                             const float* __restrict__ fc_w,
                                             const float* __restrict__ fc_b,
                                             float* __restrict__ out) {
    const int b = blockIdx.x;
    __shared__ __align__(16) float p_sh[2 * HH];
    const int t = threadIdx.x;
    if (t < 2 * HH) p_sh[t] = pool[(long)b * (2 * HH) + t];
    __syncthreads();
    if (t < OUTD) {
        const float4* wr4 = (const float4*)(fc_w + (long)t * (2 * HH));
        const float4* p4 = (const float4*)p_sh;
        float a0 = 0.f, a1 = 0.f;
#pragma unroll
        for (int k = 0; k < 50; k += 2) {
            float4 w0 = wr4[k],   p0 = p4[k];
            float4 w1 = wr4[k+1], p1 = p4[k+1];
            a0 += w0.x*p0.x + w0.y*p0.y + w0.z*p0.z + w0.w*p0.w;
            a1 += w1.x*p1.x + w1.y*p1.y + w1.z*p1.z + w1.w*p1.w;
        }
        out[(long)b * OUTD + t] = fc_b[t] + a0 + a1;
    }
}

extern "C" void kernel_launch(void* const* d_in, const int* in_sizes, int n_in,
                              void* d_out, int out_size, void* d_ws, size_t ws_size,
                              hipStream_t stream) {
    const int*   tok    = (const int*)d_in[0];
    const float* emb    = (const float*)d_in[4];
    const float* w_lin  = (const float*)d_in[5];
    const float* b_lin  = (const float*)d_in[6];
    const float* w_ih_f = (const float*)d_in[7];
    const float* w_hh_f = (const float*)d_in[8];
    const float* b_ih_f = (const float*)d_in[9];
    const float* b_hh_f = (const float*)d_in[10];
    const float* w_ih_b = (const float*)d_in[11];
    const float* w_hh_b = (const float*)d_in[12];
    const float* b_ih_b = (const float*)d_in[13];
    const float* b_hh_b = (const float*)d_in[14];
    const float* fc_w   = (const float*)d_in[15];
    const float* fc_b   = (const float*)d_in[16];

    char* wsb = (char*)d_ws;
    _Float16* wl    = (_Float16*)(wsb);             // 32768 B
    _Float16* k2b   = (_Float16*)(wsb + 32768);     // 163840 B
    _Float16* thi   = (_Float16*)(wsb + 196608);    // 3276800 B
    float*    gx    = (float*)(wsb + 3473408);      // 30720000 B
    _Float16* emb16 = (_Float16*)(wsb + 3473408);   // aliases gx: k0->k1 use, k2 overwrites
    float*    pool  = (float*)(wsb);                // aliases wl/k2b: k3 runs after k2
    float*    out   = (float*)d_out;

    k0_prep<<<11 + 3125, 256, 0, stream>>>(w_lin, w_ih_f, w_ih_b, emb, wl, k2b, emb16);
    k1_mfma<<<NTREE / K1_TPI, 256, 0, stream>>>(tok, emb16, wl, b_lin, thi);
    k2_mfma<<<(NTREE / 32) * 10, 256, 0, stream>>>(thi, k2b, b_ih_f, b_ih_b, gx);
    k3_gru <<<2 * BB, 256, 0, stream>>>(gx, w_hh_f, b_hh_f, w_hh_b, b_hh_b, pool);
    k4_fc  <<<BB, 256, 0, stream>>>(pool, fc_w, fc_b, out);
}

// Round 2
// 230.868 us; speedup vs baseline: 1.0692x; 1.0692x over previous
//
#include <hip/hip_runtime.h>
#include <hip/hip_bf16.h>
#include <math.h>

// Problem dims (fixed by reference)
#define BB 64
#define SS 200
#define TT 32
#define VV 50000
#define EE 128
#define CC 128
#define HH 100
#define G3 300           // 3*H
#define OUTD 104
#define NTREE (BB*SS)    // 12800

typedef __attribute__((ext_vector_type(4))) float f32x4;
typedef _Float16 f16x8 __attribute__((ext_vector_type(8)));

__device__ inline float fast_sigmoid(float x) {
    return __builtin_amdgcn_rcpf(1.f + __builtin_amdgcn_exp2f(-1.4426950408889634f * x));
}
__device__ inline float fast_tanh(float x) {
    return 1.f - 2.f * __builtin_amdgcn_rcpf(1.f + __builtin_amdgcn_exp2f(2.8853900817779268f * x));
}

// LDS-only barrier: waits ds-ops (lgkmcnt) but does NOT drain vmcnt, so in-flight
// global prefetch loads stay outstanding across the barrier (waited at use).
#define BAR() asm volatile("s_waitcnt lgkmcnt(0)\n\ts_barrier" ::: "memory")

// Workspace byte offsets (total 34.2 MB)
//   wl    @ 0        : 32768 B   (k1 W_lin fragment image, fp16)
//   k2b   @ 32768    : 163840 B  (k2 W_ih fragment image, fp16)
//   thi   @ 196608   : 3276800 B (tree_vec, fp16)
//   gx    @ 3473408  : 30720000 B (fp32)
//   emb16 @ 3473408  : 12800000 B -- ALIASES gx: k0 writes it, k1 reads it,
//                                   k2 overwrites gx only after k1 completes.
//   pool  @ 0        : 51200 B   -- aliases wl/k2b; k3 writes it AFTER k2 read them.

// ---------------- K0: weight-fragment images + fp16 embedding image (idempotent)
__global__ __launch_bounds__(256) void k0_prep(const float* __restrict__ w_lin,
                                               const float* __restrict__ w_ih_f,
                                               const float* __restrict__ w_ih_b,
                                               const float* __restrict__ emb,
                                               _Float16* __restrict__ wl,
                                               _Float16* __restrict__ k2b,
                                               _Float16* __restrict__ emb16) {
    const int tid  = threadIdx.x;
    const int wave = tid >> 6;
    const int lane = tid & 63;
    const int r = lane & 15;
    const int q = lane >> 4;
    if (blockIdx.x == 0) {
        // k1 image: wave w, lane(r,q), nt, kt -> W_lin[n=w*32+nt*16+r][k=kt*32+q*8 ..+8]
#pragma unroll
        for (int nt = 0; nt < 2; ++nt)
#pragma unroll
            for (int kt = 0; kt < 4; ++kt) {
                const int n = wave * 32 + nt * 16 + r;
                const float* src = w_lin + (long)n * EE + kt * 32 + q * 8;
                f16x8 f;
#pragma unroll
                for (int e = 0; e < 8; ++e) f[e] = (_Float16)src[e];
                *(f16x8*)&wl[(size_t)((((wave * 2 + nt) * 4 + kt) * 64) + lane) * 8] = f;
            }
    } else if (blockIdx.x <= 10) {
        // k2 image: nb, wave w, lane(r,q), kt -> W_ih[padded n = nb*64+w*16+r][k=kt*32+q*8]
        const int nb = blockIdx.x - 1;           // 0..9
        const int n = nb * 64 + wave * 16 + r;
        const int dir = (n >= 320) ? 1 : 0;
        const int j = n - dir * 320;
        const int jj = (j < G3) ? j : 0;         // pad rows clamped (results discarded)
        const float* w = dir ? w_ih_b : w_ih_f;
#pragma unroll
        for (int kt = 0; kt < 4; ++kt) {
            const float* src = w + (long)jj * EE + kt * 32 + q * 8;
            f16x8 f;
#pragma unroll
            for (int e = 0; e < 8; ++e) f[e] = (_Float16)src[e];
            *(f16x8*)&k2b[(size_t)((((nb * 4 + wave) * 4 + kt) * 64) + lane) * 8] = f;
        }
    } else {
        // fp16 embedding image: 50000*128 = 6,400,000 elems = 3125 blocks * 2048
        const long base = (long)(blockIdx.x - 11) * 2048 + (long)tid * 8;
        if (base < (long)VV * EE) {
            const float4* s = (const float4*)(emb + base);
            const float4 v0 = s[0], v1 = s[1];
            f16x8 f;
            f[0] = (_Float16)v0.x; f[1] = (_Float16)v0.y;
            f[2] = (_Float16)v0.z; f[3] = (_Float16)v0.w;
            f[4] = (_Float16)v1.x; f[5] = (_Float16)v1.y;
            f[6] = (_Float16)v1.z; f[7] = (_Float16)v1.w;
            *(f16x8*)&emb16[base] = f;
        }
    }
}

// ---------------- K1 (fp16 MFMA): embed-gather (fp16) -> GEMM vs W_lin^T -> bias -> tree-sum -> maxpool
#define K1_TPI 2
#define AROWS (K1_TPI*TT)        // 64
#define LDA 136                  // fp16/row: 128 + 8 pad
#define LDC 132                  // fp32/row: 128 + 4 pad

__global__ __launch_bounds__(256) void k1_mfma(const int* __restrict__ tok,
                                               const _Float16* __restrict__ emb16,
                                               const _Float16* __restrict__ wl,
                                               const float* __restrict__ b_lin,
                                               _Float16* __restrict__ thi) {
    __shared__ __align__(16) _Float16 A_sh[AROWS * LDA];   // 17408 B
    __shared__ __align__(16) float C_sh[AROWS * LDC];      // 33792 B
    __shared__ int tok_sh[AROWS];

    const int tid  = threadIdx.x;
    const int wave = tid >> 6;
    const int lane = tid & 63;
    const int r = lane & 15;
    const int q = lane >> 4;

    // ---- B fragments: 8 coalesced 16B loads from the prebuilt image (no cvt VALU)
    f16x8 bfrag[2][4];
    float bias[2];
#pragma unroll
    for (int nt = 0; nt < 2; ++nt) {
        bias[nt] = b_lin[wave * 32 + nt * 16 + r];
#pragma unroll
        for (int kt = 0; kt < 4; ++kt)
            bfrag[nt][kt] = *(const f16x8*)&wl[(size_t)((((wave * 2 + nt) * 4 + kt) * 64) + lane) * 8];
    }

    const int tree0 = blockIdx.x * K1_TPI;
    if (tid < AROWS) tok_sh[tid] = tok[tree0 * TT + tid];
    __syncthreads();

    // ---- gather fp16 embeddings -> LDS (pure 16B copies, half the global traffic)
#pragma unroll
    for (int i = 0; i < 4; ++i) {
        const int idx = tid + i * 256;       // 0..1023
        const int row = idx >> 4;            // 64 rows
        const int p   = idx & 15;            // 16 x f16x8 = 128 elems
        const f16x8 v = *(const f16x8*)&emb16[(long)tok_sh[row] * EE + p * 8];
        *(f16x8*)&A_sh[row * LDA + p * 8] = v;
    }
    __syncthreads();

    f32x4 acc[4][2];
#pragma unroll
    for (int mt = 0; mt < 4; ++mt)
#pragma unroll
        for (int nt = 0; nt < 2; ++nt) acc[mt][nt] = (f32x4)(0.f);

#pragma unroll
    for (int mt = 0; mt < 4; ++mt) {
        const int m = mt * 16 + r;
        f16x8 afrag[4];
#pragma unroll
        for (int kt = 0; kt < 4; ++kt)
            afrag[kt] = *(const f16x8*)&A_sh[m * LDA + kt * 32 + q * 8];
#pragma unroll
        for (int nt = 0; nt < 2; ++nt)
#pragma unroll
            for (int kt = 0; kt < 4; ++kt)
                acc[mt][nt] = __builtin_amdgcn_mfma_f32_16x16x32_f16(
                    afrag[kt], bfrag[nt][kt], acc[mt][nt], 0, 0, 0);
    }

#pragma unroll
    for (int mt = 0; mt < 4; ++mt)
#pragma unroll
        for (int nt = 0; nt < 2; ++nt) {
            const int col = wave * 32 + nt * 16 + r;
#pragma unroll
            for (int reg = 0; reg < 4; ++reg) {
                const int row = mt * 16 + q * 4 + reg;
                C_sh[row * LDC + col] = acc[mt][nt][reg] + bias[nt];
            }
        }
    __syncthreads();

    // ---- tree-sum + maxpool in registers (descending index = topological order)
    {
        const int t = tid >> 7;
        const int j = tid & 127;
        const float* base = &C_sh[(t * TT) * LDC + j];
        float v[TT];
#pragma unroll
        for (int n = 0; n < TT; ++n) v[n] = base[n * LDC];
        float mx = -1e30f;
#pragma unroll
        for (int n = TT - 1; n >= 1; --n) {
            mx = fmaxf(mx, v[n]);
            v[(n - 1) >> 1] += v[n];
        }
        mx = fmaxf(mx, v[0]);
        thi[(size_t)(tree0 + t) * CC + j] = (_Float16)mx;   // fp32 sums, one fp16 round
    }
}

// ---------------- K2 (fp16 MFMA): gx[dir][m=b*S+s][300] = X @ W_ih^T + b_ih
__global__ __launch_bounds__(256) void k2_mfma(const _Float16* __restrict__ thi,
                                               const _Float16* __restrict__ k2b,
                                               const float* __restrict__ b_ih_f,
                                               const float* __restrict__ b_ih_b,
                                               float* __restrict__ gx) {
    __shared__ __align__(16) _Float16 Ah[32 * LDA];   // 8704 B

    const int tid  = threadIdx.x;
    const int wave = tid >> 6;
    const int lane = tid & 63;
    const int r = lane & 15;
    const int q = lane >> 4;

    const int nb = blockIdx.x % 10;
    const int mb = blockIdx.x / 10;
    const int m0 = mb * 32;
    const int n0 = nb * 64;

    // stage A: 32 rows x 128 fp16 = 512 f16x8; 2 per thread (copy, no conversion)
#pragma unroll
    for (int i = 0; i < 2; ++i) {
        const int idx = tid + i * 256;
        const int row = idx >> 4;
        const int p   = idx & 15;
        f16x8 v = *(const f16x8*)&thi[(size_t)(m0 + row) * CC + p * 8];
        *(f16x8*)&Ah[row * LDA + p * 8] = v;
    }
    // B fragments: 4 coalesced 16B loads
    f16x8 bh[4];
#pragma unroll
    for (int kt = 0; kt < 4; ++kt)
        bh[kt] = *(const f16x8*)&k2b[(size_t)((((nb * 4 + wave) * 4 + kt) * 64) + lane) * 8];
    __syncthreads();

    f32x4 acc[2];
    acc[0] = (f32x4)(0.f); acc[1] = (f32x4)(0.f);
#pragma unroll
    for (int mt = 0; mt < 2; ++mt) {
        const int m = mt * 16 + r;
#pragma unroll
        for (int kt = 0; kt < 4; ++kt) {
            f16x8 a = *(const f16x8*)&Ah[m * LDA + kt * 32 + q * 8];
            acc[mt] = __builtin_amdgcn_mfma_f32_16x16x32_f16(a, bh[kt], acc[mt], 0, 0, 0);
        }
    }

    const int ng  = n0 + wave * 16 + r;
    const int dir = (ng >= 320) ? 1 : 0;
    const int j   = ng - dir * 320;
    const bool valid = (j < G3);
    const float bias = valid ? (dir ? b_ih_b[j] : b_ih_f[j]) : 0.f;
    float* gxd = gx + (long)dir * NTREE * G3;
    if (valid) {
#pragma unroll
        for (int mt = 0; mt < 2; ++mt)
#pragma unroll
            for (int reg = 0; reg < 4; ++reg) {
                const int m = m0 + mt * 16 + q * 4 + reg;
                gxd[(long)m * G3 + j] = acc[mt][reg] + bias;
            }
    }
}

// ---------------- K3 v7: 1 chain/block, fp16 MFMA matvec, row-permuted W_hh.
// Change vs v6 (measured 103 us, period ~1240 cyc/step, ~850 cyc idle):
//  - TRUE deep prefetch of gx. v5/v6 rotated prefetch registers at the bottom of
//    the SAME iteration that issued the load (xr1=xr2), forcing the vmcnt wait
//    ~300 cyc after issue while gx is L3/HBM-resident (~600-900 cyc) -> ~500-700
//    cyc stall per step regardless of nominal depth. v7 unrolls the t-loop by 4
//    with four NAMED buffers (compile-time index, no rotation movs): load for
//    step t+4 issues in body j, first read 4 full step-periods later -> counted
//    vmcnt, latency fully hidden.
__global__ __launch_bounds__(256, 1) void k3_gru(const float* __restrict__ gx,
                                                 const float* __restrict__ w_hh_f,
                                                 const float* __restrict__ b_hh_f,
                                                 const float* __restrict__ w_hh_b,
                                                 const float* __restrict__ b_hh_b,
                                                 float* __restrict__ pool) {
    const int bid = blockIdx.x;   // 0..127
    const int dir = bid & 1;
    const int b = bid >> 1;
    const float* w_hh = dir ? w_hh_b : w_hh_f;
    const float* b_hh = dir ? b_hh_b : b_hh_f;

    __shared__ __align__(16) _Float16 h_sh[2][128];

    const int tid  = threadIdx.x;
    const int wave = tid >> 6;
    const int lane = tid & 63;
    const int r = lane & 15;
    const int q = lane >> 4;

    // W_hh fragments, row-permuted: tile i, lane r -> l=i*16+r; gate=l/25, ch=l-25*gate;
    // actual row = gate*H + wave*25 + ch  (rows l>=75 zero-padded)
    f16x8 bf[5][4];
#pragma unroll
    for (int i = 0; i < 5; ++i) {
        const int l = i * 16 + r;
        const int gate = l / 25;
        const int ch   = l - gate * 25;
        const bool nv  = (l < 75);
        const int row  = gate * HH + wave * 25 + ch;
#pragma unroll
        for (int kt = 0; kt < 4; ++kt) {
            f16x8 f;
#pragma unroll
            for (int e = 0; e < 8; ++e) {
                const int k = kt * 32 + q * 8 + e;
                f[e] = (_Float16)((nv && k < HH) ? w_hh[row * HH + k] : 0.f);
            }
            bf[i][kt] = f;
        }
    }

    const int m = lane;
    const int c = wave * 25 + m;
    const bool act = (m < 25);
    float br = 0.f, bz = 0.f, bn = 0.f;
    if (act) { br = b_hh[c]; bz = b_hh[HH + c]; bn = b_hh[2 * HH + c]; }

    // bpermute source lanes: V1 at lane l holds gh[l] (l<64); g4 at lane r holds gh[64+r]
    const int a_z  = (25 + m) & 63;          // row 25+m
    const int a_n1 = (50 + m) & 63;          // row 50+m if < 64
    const int a_n2 = (50 + m - 64) & 63;     // row 50+m if >= 64 (from g4)
    const bool nV1 = (50 + m) < 64;

    if (tid < 128) { h_sh[0][tid] = (_Float16)0.f; h_sh[1][tid] = (_Float16)0.f; }

    const float* gxd = gx + (long)dir * NTREE * G3;
    const int sstep = dir ? -1 : 1;
    const int s0 = dir ? (SS - 1) : 0;
    // lane-local base pointer into this chain's gx rows (valid for act lanes)
    const float* gp = gxd + (long)b * SS * G3 + c;

    // 4-deep prefetch, NAMED buffers (indices become literals after full unroll)
    float pxr[4], pxz[4], pxn[4];
    if (act) {
#pragma unroll
        for (int j = 0; j < 4; ++j) {
            const long off = (long)(s0 + j * sstep) * G3;
            pxr[j] = gp[off]; pxz[j] = gp[off + HH]; pxn[j] = gp[off + 2 * HH];
        }
    }
    float hj = 0.f, hmax = -1e30f;
    __syncthreads();

    int s = s0;
    for (int t = 0; t < SS; t += 4) {
#pragma unroll
        for (int j = 0; j < 4; ++j) {
            const int p = j & 1;             // (t+j)&1, t multiple of 4

            f16x8 a[4];
#pragma unroll
            for (int kt = 0; kt < 4; ++kt)
                a[kt] = *(const f16x8*)&h_sh[p][kt * 32 + q * 8];

            // split-K: two parallel depth-2 chains per tile
            f32x4 accA[5], accB[5];
#pragma unroll
            for (int i = 0; i < 5; ++i) {
                accA[i] = (f32x4)(0.f);
                accB[i] = (f32x4)(0.f);
                accA[i] = __builtin_amdgcn_mfma_f32_16x16x32_f16(a[0], bf[i][0], accA[i], 0, 0, 0);
                accB[i] = __builtin_amdgcn_mfma_f32_16x16x32_f16(a[2], bf[i][2], accB[i], 0, 0, 0);
                accA[i] = __builtin_amdgcn_mfma_f32_16x16x32_f16(a[1], bf[i][1], accA[i], 0, 0, 0);
                accB[i] = __builtin_amdgcn_mfma_f32_16x16x32_f16(a[3], bf[i][3], accB[i], 0, 0, 0);
            }
            const float g0 = accA[0][0] + accB[0][0];
            const float g1 = accA[1][0] + accB[1][0];
            const float g2 = accA[2][0] + accB[2][0];
            const float g3 = accA[3][0] + accB[3][0];
            const float g4 = accA[4][0] + accB[4][0];
            // V1 at lane l = gh[row l] (rows 0..63); g4 at lane r = gh[64+r] (rows 64..74)
            float V1 = g0;
            V1 = (q == 1) ? g1 : V1;
            V1 = (q == 2) ? g2 : V1;
            V1 = (q == 3) ? g3 : V1;
            const float ghr = V1;                    // row m == own lane
            const float ghz = __shfl(V1, a_z);       // row 25+m
            const float vnA = __shfl(V1, a_n1);
            const float vnB = __shfl(g4, a_n2);
            const float ghn = nV1 ? vnA : vnB;       // row 50+m

            if (act) {
                const float rg = fast_sigmoid(pxr[j] + ghr + br);
                const float zg = fast_sigmoid(pxz[j] + ghz + bz);
                const float ng = fast_tanh(pxn[j] + rg * (ghn + bn));
                hj = (1.f - zg) * ng + zg * hj;
                h_sh[1 - p][c] = (_Float16)hj;
                hmax = fmaxf(hmax, hj);
                // refill this slot for step t+j+4 (consumed 4 step-periods from now)
                if (t + j + 4 < SS) {
                    const long off = (long)(s + (j + 4) * sstep) * G3;
                    pxr[j] = gp[off]; pxz[j] = gp[off + HH]; pxn[j] = gp[off + 2 * HH];
                }
            }
            BAR();
        }
        s += 4 * sstep;
    }
    if (act) pool[(long)b * (2 * HH) + dir * HH + c] = hmax;
}

// ---------------- K4: out[b][o] = fc_b[o] + pool[b,:] . fc_w[o,:]
__global__ __launch_bounds__(256) void k4_fc(const float* __restrict__ pool,
                                             const float* __restrict__ fc_w,
                                             const float* __restrict__ fc_b,
                                             float* __restrict__ out) {
    const int b = blockIdx.x;
    __shared__ __align__(16) float p_sh[2 * HH];
    const int t = threadIdx.x;
    if (t < 2 * HH) p_sh[t] = pool[(long)b * (2 * HH) + t];
    __syncthreads();
    if (t < OUTD) {
        const float4* wr4 = (const float4*)(fc_w + (long)t * (2 * HH));
        const float4* p4 = (const float4*)p_sh;
        float a0 = 0.f, a1 = 0.f;
#pragma unroll
        for (int k = 0; k < 50; k += 2) {
            float4 w0 = wr4[k],   p0 = p4[k];
            float4 w1 = wr4[k+1], p1 = p4[k+1];
            a0 += w0.x*p0.x + w0.y*p0.y + w0.z*p0.z + w0.w*p0.w;
            a1 += w1.x*p1.x + w1.y*p1.y + w1.z*p1.z + w1.w*p1.w;
        }
        out[(long)b * OUTD + t] = fc_b[t] + a0 + a1;
    }
}

extern "C" void kernel_launch(void* const* d_in, const int* in_sizes, int n_in,
                              void* d_out, int out_size, void* d_ws, size_t ws_size,
                              hipStream_t stream) {
    const int*   tok    = (const int*)d_in[0];
    const float* emb    = (const float*)d_in[4];
    const float* w_lin  = (const float*)d_in[5];
    const float* b_lin  = (const float*)d_in[6];
    const float* w_ih_f = (const float*)d_in[7];
    const float* w_hh_f = (const float*)d_in[8];
    const float* b_ih_f = (const float*)d_in[9];
    const float* b_hh_f = (const float*)d_in[10];
    const float* w_ih_b = (const float*)d_in[11];
    const float* w_hh_b = (const float*)d_in[12];
    const float* b_ih_b = (const float*)d_in[13];
    const float* b_hh_b = (const float*)d_in[14];
    const float* fc_w   = (const float*)d_in[15];
    const float* fc_b   = (const float*)d_in[16];

    char* wsb = (char*)d_ws;
    _Float16* wl    = (_Float16*)(wsb);             // 32768 B
    _Float16* k2b   = (_Float16*)(wsb + 32768);     // 163840 B
    _Float16* thi   = (_Float16*)(wsb + 196608);    // 3276800 B
    float*    gx    = (float*)(wsb + 3473408);      // 30720000 B
    _Float16* emb16 = (_Float16*)(wsb + 3473408);   // aliases gx: k0->k1 use, k2 overwrites
    float*    pool  = (float*)(wsb);                // aliases wl/k2b: k3 runs after k2
    float*    out   = (float*)d_out;

    k0_prep<<<11 + 3125, 256, 0, stream>>>(w_lin, w_ih_f, w_ih_b, emb, wl, k2b, emb16);
    k1_mfma<<<NTREE / K1_TPI, 256, 0, stream>>>(tok, emb16, wl, b_lin, thi);
    k2_mfma<<<(NTREE / 32) * 10, 256, 0, stream>>>(thi, k2b, b_ih_f, b_ih_b, gx);
    k3_gru <<<2 * BB, 256, 0, stream>>>(gx, w_hh_f, b_hh_f, w_hh_b, b_hh_b, pool);
    k4_fc  <<<BB, 256, 0, stream>>>(pool, fc_w, fc_b, out);
}